// Round 6
// baseline (244.772 us; speedup 1.0000x reference)
//
#include <hip/hip_runtime.h>
#include <hip/hip_fp16.h>

#define N_NODES 100000
#define N_EDGES 1600000
#define K_DIM   128

#define CHUNK_LG 10
#define CHUNK    1024                                    // nodes per bucket
#define NBKT     ((N_NODES + CHUNK - 1) / CHUNK)         // 98
#define CAP      18432
#define EPB      4096                                    // edges per phase-A block
#define NBLK_A   ((N_EDGES + EPB - 1) / EPB)             // 391

typedef _Float16 half8 __attribute__((ext_vector_type(8)));
typedef float    f32x4 __attribute__((ext_vector_type(4)));

// ---------------- CSR build, bucketed ----------------

// Phase A: partition edges into NBKT bucket regions as packed 4B entries.
__global__ __launch_bounds__(256) void k_bucket(const int* __restrict__ row,
                                                const int* __restrict__ col,
                                                int* __restrict__ gcur,
                                                int* __restrict__ pairs) {
    __shared__ int hist[NBKT], sbase[NBKT], lcur[NBKT];
    int t = threadIdx.x;
    if (t < NBKT) { hist[t] = 0; lcur[t] = 0; }
    __syncthreads();
    int base = blockIdx.x * EPB;
    int myb[16], myp[16];
#pragma unroll
    for (int j = 0; j < 16; ++j) {
        int i = base + t + j * 256;
        int b = -1, p = 0;
        if (i < N_EDGES) {
            int r = row[i], c = col[i];
            b = c >> CHUNK_LG;
            p = ((c & (CHUNK - 1)) << 17) | r;     // row < 2^17
            atomicAdd(&hist[b], 1);
        }
        myb[j] = b; myp[j] = p;
    }
    __syncthreads();
    if (t < NBKT) {
        int c = hist[t];
        sbase[t] = c ? atomicAdd(&gcur[t], c) : 0;
    }
    __syncthreads();
#pragma unroll
    for (int j = 0; j < 16; ++j) {
        int b = myb[j];
        if (b >= 0) {
            int pos = sbase[b] + atomicAdd(&lcur[b], 1);
            pairs[b * CAP + pos] = myp[j];
        }
    }
}

// Phase B: one block per bucket; computes its own global base from gcur
// (98-entry LDS scan); local hist+scan -> rowptr/dinv; fill srows.
__global__ __launch_bounds__(256) void k_fillB(const int* __restrict__ gcur,
                                               const int* __restrict__ pairs,
                                               int* __restrict__ rowptr,
                                               float* __restrict__ dinv,
                                               int* __restrict__ srows) {
    __shared__ int pre[128];
    __shared__ int deg[CHUNK];
    __shared__ int curs[CHUNK];
    __shared__ int psum[256];
    int b = blockIdx.x, t = threadIdx.x;

    if (t < 128) pre[t] = (t < NBKT) ? gcur[t] : 0;
    __syncthreads();
    for (int off = 1; off < 128; off <<= 1) {
        int u = (t >= off && t < 128) ? pre[t - off] : 0;
        __syncthreads();
        if (t < 128) pre[t] += u;
        __syncthreads();
    }
    int gb = (b == 0) ? 0 : pre[b - 1];
    int cnt = gcur[b];
    if (b == 0 && t == 0) rowptr[N_NODES] = N_EDGES;

    int nbase = b << CHUNK_LG;
    int nn = min(CHUNK, N_NODES - nbase);
    const int* mp = pairs + b * CAP;

    for (int i = t; i < CHUNK; i += 256) deg[i] = 0;
    __syncthreads();
    for (int i = t; i < cnt; i += 256) atomicAdd(&deg[mp[i] >> 17], 1);
    __syncthreads();

    int i0 = t * 4;
    int d0 = deg[i0], d1 = deg[i0 + 1], d2 = deg[i0 + 2], d3 = deg[i0 + 3];
    int s4 = d0 + d1 + d2 + d3;
    psum[t] = s4;
    __syncthreads();
    for (int off = 1; off < 256; off <<= 1) {
        int u = (t >= off) ? psum[t - off] : 0;
        __syncthreads();
        psum[t] += u;
        __syncthreads();
    }
    int ex = gb + psum[t] - s4;
    int o0 = ex, o1 = o0 + d0, o2 = o1 + d1, o3 = o2 + d2;
    curs[i0] = o0; curs[i0 + 1] = o1; curs[i0 + 2] = o2; curs[i0 + 3] = o3;
    if (i0 + 3 < nn) {
        *reinterpret_cast<int4*>(rowptr + nbase + i0) = make_int4(o0, o1, o2, o3);
        float4 dv = make_float4(rsqrtf(1.f + (float)d0), rsqrtf(1.f + (float)d1),
                                rsqrtf(1.f + (float)d2), rsqrtf(1.f + (float)d3));
        *reinterpret_cast<float4*>(dinv + nbase + i0) = dv;
    } else {
        int oo[4] = {o0, o1, o2, o3};
        int dd[4] = {d0, d1, d2, d3};
        for (int j = 0; j < 4; ++j) if (i0 + j < nn) {
            rowptr[nbase + i0 + j] = oo[j];
            dinv[nbase + i0 + j] = rsqrtf(1.f + (float)dd[j]);
        }
    }
    __syncthreads();
    for (int i = t; i < cnt; i += 256) {
        int v = mp[i];
        int pos = atomicAdd(&curs[v >> 17], 1);
        srows[pos] = v & 0x1FFFF;
    }
}

// ---------------- f16 MFMA GEMM: H = A' @ W,  H stored f16 ----------------
template<int NOUT, bool A_HALF_RELU>
__global__ __launch_bounds__(256) void k_gemm_mfma(
    const float* __restrict__ Af, const _Float16* __restrict__ Ah,
    const float* __restrict__ W, const float* __restrict__ b_in,
    _Float16* __restrict__ Hout, int nrows)
{
    constexpr int KD = K_DIM;
    constexpr int NT = NOUT / 16;
    __shared__ _Float16 Blds[NOUT][KD + 8];

    for (int i = threadIdx.x * 4; i < KD * NOUT; i += 256 * 4) {
        int k = i / NOUT, n = i % NOUT;      // W row-major [KD][NOUT]
        float4 wv = *reinterpret_cast<const float4*>(W + i);
        Blds[n + 0][k] = (_Float16)wv.x;
        Blds[n + 1][k] = (_Float16)wv.y;
        Blds[n + 2][k] = (_Float16)wv.z;
        Blds[n + 3][k] = (_Float16)wv.w;
    }
    __syncthreads();

    const int wave = threadIdx.x >> 6;
    const int lane = threadIdx.x & 63;
    const int r16  = lane & 15;
    const int kg   = lane >> 4;
    const int row  = blockIdx.x * 64 + wave * 16 + r16;
    const bool rowok = row < nrows;

    f32x4 acc[NT];
#pragma unroll
    for (int ct = 0; ct < NT; ++ct) acc[ct] = (f32x4){0.f, 0.f, 0.f, 0.f};

#pragma unroll
    for (int kc = 0; kc < KD / 32; ++kc) {
        const int k0 = kc * 32 + kg * 8;
        half8 a;
        if constexpr (A_HALF_RELU) {
            uint4 raw = make_uint4(0, 0, 0, 0);
            if (rowok)
                raw = *reinterpret_cast<const uint4*>(Ah + (size_t)row * KD + k0);
            union { uint4 u; _Float16 h[8]; } U; U.u = raw;
            float4 bA = *reinterpret_cast<const float4*>(b_in + k0);
            float4 bB = *reinterpret_cast<const float4*>(b_in + k0 + 4);
            a[0] = (_Float16)fmaxf((float)U.h[0] + bA.x, 0.f);
            a[1] = (_Float16)fmaxf((float)U.h[1] + bA.y, 0.f);
            a[2] = (_Float16)fmaxf((float)U.h[2] + bA.z, 0.f);
            a[3] = (_Float16)fmaxf((float)U.h[3] + bA.w, 0.f);
            a[4] = (_Float16)fmaxf((float)U.h[4] + bB.x, 0.f);
            a[5] = (_Float16)fmaxf((float)U.h[5] + bB.y, 0.f);
            a[6] = (_Float16)fmaxf((float)U.h[6] + bB.z, 0.f);
            a[7] = (_Float16)fmaxf((float)U.h[7] + bB.w, 0.f);
        } else {
            float4 xa = make_float4(0.f, 0.f, 0.f, 0.f), xb = xa;
            if (rowok) {
                const float4* ap = reinterpret_cast<const float4*>(
                    Af + (size_t)row * KD + k0);
                xa = ap[0]; xb = ap[1];
            }
            a[0] = (_Float16)xa.x; a[1] = (_Float16)xa.y;
            a[2] = (_Float16)xa.z; a[3] = (_Float16)xa.w;
            a[4] = (_Float16)xb.x; a[5] = (_Float16)xb.y;
            a[6] = (_Float16)xb.z; a[7] = (_Float16)xb.w;
        }
#pragma unroll
        for (int ct = 0; ct < NT; ++ct) {
            half8 b = *reinterpret_cast<const half8*>(&Blds[ct * 16 + r16][k0]);
            acc[ct] = __builtin_amdgcn_mfma_f32_16x16x32_f16(a, b, acc[ct], 0, 0, 0);
        }
    }

    const int orow0 = blockIdx.x * 64 + wave * 16 + kg * 4;
#pragma unroll
    for (int r = 0; r < 4; ++r) {
        int orow = orow0 + r;
        if (orow < nrows) {
#pragma unroll
            for (int ct = 0; ct < NT; ++ct)
                Hout[(size_t)orow * NOUT + ct * 16 + r16] = (_Float16)acc[ct][r];
        }
    }
}

// ---------------- gather (f16 source): one wave per destination ----------
// fma_mix pattern: f32 = f16*f32 + f32 (no separate cvt)
__device__ __forceinline__ void fma8(uint4 v, float wgt, float (&acc)[8]) {
    union { uint4 u; _Float16 h[8]; } U;
    U.u = v;
#pragma unroll
    for (int j = 0; j < 8; ++j)
        acc[j] = fmaf((float)U.h[j], wgt, acc[j]);
}

// OUT[i] = sum_e H[row_e]*dinv_r*dinv_i + H[i]*dinv_i^2 (+bias)
template<int F, bool OUT_HALF, int UNR>
__global__ __launch_bounds__(256) void k_gather_h(
    const int* __restrict__ rowptr, const int* __restrict__ srows,
    const float* __restrict__ dinv, const _Float16* __restrict__ H,
    const float* __restrict__ bias, void* __restrict__ OUT, int n)
{
    constexpr int LPR = F / 8;     // lanes per row (16 or 8), 8 f16 per lane
    constexpr int GR  = 64 / LPR;  // rows per wave-load (4 or 8)
    int w = blockIdx.x * 4 + (threadIdx.x >> 6);
    if (w >= n) return;
    int lane = threadIdx.x & 63;
    int g = lane / LPR;
    int c = lane % LPR;            // uint4 slot within row
    float di = dinv[w];
    int s = rowptr[w], e = rowptr[w + 1];
    const uint4* Hp = reinterpret_cast<const uint4*>(H);

    float acc[8];
#pragma unroll
    for (int j = 0; j < 8; ++j) acc[j] = 0.f;
    uint4 hv = Hp[(size_t)w * LPR + c];                 // self row
    fma8(hv, (g == 0) ? di * di : 0.f, acc);

    for (int k = s; k < e; k += UNR * GR) {
        float ww[UNR]; uint4 hh[UNR];
#pragma unroll
        for (int u = 0; u < UNR; ++u) {
            int ki = k + u * GR + g;
            int kc = min(ki, e - 1);
            int r = srows[kc];
            ww[u] = (ki < e) ? dinv[r] * di : 0.f;
            hh[u] = Hp[(size_t)r * LPR + c];
        }
#pragma unroll
        for (int u = 0; u < UNR; ++u) fma8(hh[u], ww[u], acc);
    }

#pragma unroll
    for (int m = 32; m >= LPR; m >>= 1) {
#pragma unroll
        for (int j = 0; j < 8; ++j)
            acc[j] += __shfl_xor(acc[j], m, 64);
    }

    if (g == 0) {
        if constexpr (OUT_HALF) {
            union { uint4 u; __half2 h[4]; } P;
#pragma unroll
            for (int j = 0; j < 4; ++j)
                P.h[j] = __floats2half2_rn(acc[2 * j], acc[2 * j + 1]);
            reinterpret_cast<uint4*>(OUT)[(size_t)w * LPR + c] = P.u;
        } else {
            const float4* bp = reinterpret_cast<const float4*>(bias + c * 8);
            float4 b0 = bp[0], b1 = bp[1];
            float4 o0 = make_float4(acc[0] + b0.x, acc[1] + b0.y,
                                    acc[2] + b0.z, acc[3] + b0.w);
            float4 o1 = make_float4(acc[4] + b1.x, acc[5] + b1.y,
                                    acc[6] + b1.z, acc[7] + b1.w);
            float* op = (float*)OUT + (size_t)w * F + c * 8;
            *reinterpret_cast<float4*>(op)     = o0;
            *reinterpret_cast<float4*>(op + 4) = o1;
        }
    }
}

// ---------------- launch ----------------

extern "C" void kernel_launch(void* const* d_in, const int* in_sizes, int n_in,
                              void* d_out, int out_size, void* d_ws, size_t ws_size,
                              hipStream_t stream) {
    const float* x  = (const float*)d_in[0];
    const int*   ei = (const int*)  d_in[1];
    const float* W1 = (const float*)d_in[2];
    const float* b1 = (const float*)d_in[3];
    const float* W2 = (const float*)d_in[4];
    const float* b2 = (const float*)d_in[5];
    float* out = (float*)d_out;

    const int* row = ei;             // sources
    const int* col = ei + N_EDGES;   // targets

    // workspace layout
    char* ws = (char*)d_ws;
    int*   gcur   = (int*)ws;                                      // NBKT
    int*   rowptr = gcur + 128;                                    // N+1
    float* dinv   = (float*)(rowptr + ((N_NODES + 256) & ~255));   // N
    int*   srows  = (int*)(dinv + ((N_NODES + 255) & ~255));       // E
    _Float16* bufH   = (_Float16*)(srows + ((N_EDGES + 255) & ~255)); // N*128 f16
    _Float16* bufAgg = bufH + (size_t)N_NODES * 128;               // N*128 f16
    int*   pairs  = (int*)bufAgg;    // 7.2MB, dead before gather1

    // 1) CSR by destination + dinv
    hipMemsetAsync(gcur, 0, NBKT * sizeof(int), stream);
    k_bucket<<<NBLK_A, 256, 0, stream>>>(row, col, gcur, pairs);
    k_fillB <<<NBKT, 256, 0, stream>>>(gcur, pairs, rowptr, dinv, srows);

    // 2) h1 = x@W1 (f16 out)
    k_gemm_mfma<128, false><<<(N_NODES + 63) / 64, 256, 0, stream>>>(
        x, nullptr, W1, nullptr, bufH, N_NODES);

    // 3) agg1 = gather(h1), f16 out
    k_gather_h<128, true, 4><<<(N_NODES + 3) / 4, 256, 0, stream>>>(
        rowptr, srows, dinv, bufH, nullptr, bufAgg, N_NODES);

    // 4) h2 = relu(agg1+b1)@W2 (f16 out)
    k_gemm_mfma<64, true><<<(N_NODES + 63) / 64, 256, 0, stream>>>(
        nullptr, bufAgg, W2, b1, bufH, N_NODES);

    // 5) out = gather(h2) + b2 (fp32 out)
    k_gather_h<64, false, 2><<<(N_NODES + 3) / 4, 256, 0, stream>>>(
        rowptr, srows, dinv, bufH, b2, out, N_NODES);
}

// Round 7
// 201.113 us; speedup vs baseline: 1.2171x; 1.2171x over previous
//
#include <hip/hip_runtime.h>
#include <hip/hip_fp16.h>

#define N_NODES 100000
#define N_EDGES 1600000
#define K_DIM   128

#define CHUNK_LG 8
#define CHUNK    256                                     // nodes per bucket
#define NBKT     ((N_NODES + CHUNK - 1) / CHUNK)         // 391
#define CAP      4608                                    // mean 4096, sigma 64
#define EPB      4096                                    // edges per bucket-block
#define NBLK_A   ((N_EDGES + EPB - 1) / EPB)             // 391
#define G1_BLOCKS ((N_NODES + 63) / 64)                  // 1563 gemm1 blocks

typedef _Float16 half8 __attribute__((ext_vector_type(8)));
typedef float    f32x4 __attribute__((ext_vector_type(4)));

// ============ fused: gemm1 (h1 = x@W1, f16 out)  +  edge bucketing ========
// blocks [0, G1_BLOCKS): MFMA GEMM.  blocks [G1_BLOCKS, +NBLK_A): partition
// edges into NBKT bucket regions as packed 4B entries (independent work).
__global__ __launch_bounds__(256) void k_gemm1_bucket(
    const float* __restrict__ x, const float* __restrict__ W,
    _Float16* __restrict__ Hout,
    const int* __restrict__ row, const int* __restrict__ col,
    int* __restrict__ gcur, int* __restrict__ pairs)
{
    __shared__ __align__(16) char smem[128 * 136 * 2];   // 34816 B

    if (blockIdx.x < G1_BLOCKS) {
        // ---------------- gemm path: NOUT=128, A fp32 ----------------
        constexpr int KD = K_DIM, NOUT = 128, NT = NOUT / 16;
        _Float16 (*Blds)[KD + 8] = reinterpret_cast<_Float16(*)[KD + 8]>(smem);

        for (int i = threadIdx.x * 4; i < KD * NOUT; i += 256 * 4) {
            int k = i / NOUT, n = i % NOUT;              // W row-major [KD][NOUT]
            float4 wv = *reinterpret_cast<const float4*>(W + i);
            Blds[n + 0][k] = (_Float16)wv.x;
            Blds[n + 1][k] = (_Float16)wv.y;
            Blds[n + 2][k] = (_Float16)wv.z;
            Blds[n + 3][k] = (_Float16)wv.w;
        }
        __syncthreads();

        const int wave = threadIdx.x >> 6;
        const int lane = threadIdx.x & 63;
        const int r16  = lane & 15;
        const int kg   = lane >> 4;
        const int arow = blockIdx.x * 64 + wave * 16 + r16;
        const bool rowok = arow < N_NODES;

        f32x4 acc[NT];
#pragma unroll
        for (int ct = 0; ct < NT; ++ct) acc[ct] = (f32x4){0.f, 0.f, 0.f, 0.f};

#pragma unroll
        for (int kc = 0; kc < KD / 32; ++kc) {
            const int k0 = kc * 32 + kg * 8;
            float4 xa = make_float4(0.f, 0.f, 0.f, 0.f), xb = xa;
            if (rowok) {
                const float4* ap = reinterpret_cast<const float4*>(
                    x + (size_t)arow * KD + k0);
                xa = ap[0]; xb = ap[1];
            }
            half8 a;
            a[0] = (_Float16)xa.x; a[1] = (_Float16)xa.y;
            a[2] = (_Float16)xa.z; a[3] = (_Float16)xa.w;
            a[4] = (_Float16)xb.x; a[5] = (_Float16)xb.y;
            a[6] = (_Float16)xb.z; a[7] = (_Float16)xb.w;
#pragma unroll
            for (int ct = 0; ct < NT; ++ct) {
                half8 b = *reinterpret_cast<const half8*>(&Blds[ct * 16 + r16][k0]);
                acc[ct] = __builtin_amdgcn_mfma_f32_16x16x32_f16(a, b, acc[ct], 0, 0, 0);
            }
        }

        const int orow0 = blockIdx.x * 64 + wave * 16 + kg * 4;
#pragma unroll
        for (int r = 0; r < 4; ++r) {
            int orow = orow0 + r;
            if (orow < N_NODES) {
#pragma unroll
                for (int ct = 0; ct < NT; ++ct)
                    Hout[(size_t)orow * NOUT + ct * 16 + r16] = (_Float16)acc[ct][r];
            }
        }
    } else {
        // ---------------- bucket path ----------------
        int* hist  = (int*)smem;           // [512]
        int* sbase = hist + 512;           // [512]
        int* lcur  = hist + 1024;          // [512]
        int t = threadIdx.x;
        for (int i = t; i < NBKT; i += 256) { hist[i] = 0; lcur[i] = 0; }
        __syncthreads();
        int base = (blockIdx.x - G1_BLOCKS) * EPB;
        int myb[16], myp[16];
#pragma unroll
        for (int j = 0; j < 16; ++j) {
            int i = base + t + j * 256;
            int b = -1, p = 0;
            if (i < N_EDGES) {
                int r = row[i], c = col[i];
                b = c >> CHUNK_LG;
                p = ((c & (CHUNK - 1)) << 17) | r;       // row < 2^17
                atomicAdd(&hist[b], 1);
            }
            myb[j] = b; myp[j] = p;
        }
        __syncthreads();
        for (int i = t; i < NBKT; i += 256) {
            int c = hist[i];
            sbase[i] = c ? atomicAdd(&gcur[i], c) : 0;
        }
        __syncthreads();
#pragma unroll
        for (int j = 0; j < 16; ++j) {
            int b = myb[j];
            if (b >= 0) {
                int pos = sbase[b] + atomicAdd(&lcur[b], 1);
                pairs[b * CAP + pos] = myp[j];
            }
        }
    }
}

// ============ Phase B: one block per bucket -> rowptr, dinv, srows ========
__global__ __launch_bounds__(256) void k_fillB(const int* __restrict__ gcur,
                                               const int* __restrict__ pairs,
                                               int* __restrict__ rowptr,
                                               float* __restrict__ dinv,
                                               int* __restrict__ srows) {
    __shared__ int red[256];
    __shared__ int psum[256];
    __shared__ int deg[CHUNK];
    __shared__ int curs[CHUNK];
    int b = blockIdx.x, t = threadIdx.x;

    // global base = sum gcur[0..b-1]
    int part = 0;
    for (int i = t; i < NBKT; i += 256)
        if (i < b) part += gcur[i];
    red[t] = part;
    __syncthreads();
    for (int off = 128; off; off >>= 1) {
        if (t < off) red[t] += red[t + off];
        __syncthreads();
    }
    int gb = red[0];
    int cnt = gcur[b];
    if (b == 0 && t == 0) rowptr[N_NODES] = N_EDGES;

    int nbase = b << CHUNK_LG;
    const int* mp = pairs + b * CAP;

    deg[t] = 0;
    __syncthreads();
    for (int i = t; i < cnt; i += 256) atomicAdd(&deg[mp[i] >> 17], 1);
    __syncthreads();

    int d = deg[t];
    psum[t] = d;
    __syncthreads();
    for (int off = 1; off < 256; off <<= 1) {
        int u = (t >= off) ? psum[t - off] : 0;
        __syncthreads();
        psum[t] += u;
        __syncthreads();
    }
    int o = gb + psum[t] - d;                 // exclusive
    curs[t] = o;
    int node = nbase + t;
    if (node < N_NODES) {
        rowptr[node] = o;
        dinv[node] = rsqrtf(1.f + (float)d);
    }
    __syncthreads();
    for (int i = t; i < cnt; i += 256) {
        int v = mp[i];
        int pos = atomicAdd(&curs[v >> 17], 1);
        srows[pos] = v & 0x1FFFF;
    }
}

// ============ layer-2 GEMM: h2 = relu(agg1+b1)@W2, f16 out ================
template<int NOUT>
__global__ __launch_bounds__(256) void k_gemm_mfma2(
    const _Float16* __restrict__ Ah, const float* __restrict__ W,
    const float* __restrict__ b_in, _Float16* __restrict__ Hout, int nrows)
{
    constexpr int KD = K_DIM;
    constexpr int NT = NOUT / 16;
    __shared__ _Float16 Blds[NOUT][KD + 8];

    for (int i = threadIdx.x * 4; i < KD * NOUT; i += 256 * 4) {
        int k = i / NOUT, n = i % NOUT;
        float4 wv = *reinterpret_cast<const float4*>(W + i);
        Blds[n + 0][k] = (_Float16)wv.x;
        Blds[n + 1][k] = (_Float16)wv.y;
        Blds[n + 2][k] = (_Float16)wv.z;
        Blds[n + 3][k] = (_Float16)wv.w;
    }
    __syncthreads();

    const int wave = threadIdx.x >> 6;
    const int lane = threadIdx.x & 63;
    const int r16  = lane & 15;
    const int kg   = lane >> 4;
    const int arow = blockIdx.x * 64 + wave * 16 + r16;
    const bool rowok = arow < nrows;

    f32x4 acc[NT];
#pragma unroll
    for (int ct = 0; ct < NT; ++ct) acc[ct] = (f32x4){0.f, 0.f, 0.f, 0.f};

#pragma unroll
    for (int kc = 0; kc < KD / 32; ++kc) {
        const int k0 = kc * 32 + kg * 8;
        uint4 raw = make_uint4(0, 0, 0, 0);
        if (rowok)
            raw = *reinterpret_cast<const uint4*>(Ah + (size_t)arow * KD + k0);
        union { uint4 u; _Float16 h[8]; } U; U.u = raw;
        float4 bA = *reinterpret_cast<const float4*>(b_in + k0);
        float4 bB = *reinterpret_cast<const float4*>(b_in + k0 + 4);
        half8 a;
        a[0] = (_Float16)fmaxf((float)U.h[0] + bA.x, 0.f);
        a[1] = (_Float16)fmaxf((float)U.h[1] + bA.y, 0.f);
        a[2] = (_Float16)fmaxf((float)U.h[2] + bA.z, 0.f);
        a[3] = (_Float16)fmaxf((float)U.h[3] + bA.w, 0.f);
        a[4] = (_Float16)fmaxf((float)U.h[4] + bB.x, 0.f);
        a[5] = (_Float16)fmaxf((float)U.h[5] + bB.y, 0.f);
        a[6] = (_Float16)fmaxf((float)U.h[6] + bB.z, 0.f);
        a[7] = (_Float16)fmaxf((float)U.h[7] + bB.w, 0.f);
#pragma unroll
        for (int ct = 0; ct < NT; ++ct) {
            half8 b = *reinterpret_cast<const half8*>(&Blds[ct * 16 + r16][k0]);
            acc[ct] = __builtin_amdgcn_mfma_f32_16x16x32_f16(a, b, acc[ct], 0, 0, 0);
        }
    }

    const int orow0 = blockIdx.x * 64 + wave * 16 + kg * 4;
#pragma unroll
    for (int r = 0; r < 4; ++r) {
        int orow = orow0 + r;
        if (orow < nrows) {
#pragma unroll
            for (int ct = 0; ct < NT; ++ct)
                Hout[(size_t)orow * NOUT + ct * 16 + r16] = (_Float16)acc[ct][r];
        }
    }
}

// ---------------- gather (f16 source): one wave per destination ----------
__device__ __forceinline__ void fma8(uint4 v, float wgt, float (&acc)[8]) {
    union { uint4 u; _Float16 h[8]; } U;
    U.u = v;
#pragma unroll
    for (int j = 0; j < 8; ++j)
        acc[j] = fmaf((float)U.h[j], wgt, acc[j]);
}

// OUT[i] = sum_e H[row_e]*dinv_r*dinv_i + H[i]*dinv_i^2 (+bias)   [R5 form]
template<int F, bool OUT_HALF>
__global__ __launch_bounds__(256) void k_gather_h(
    const int* __restrict__ rowptr, const int* __restrict__ srows,
    const float* __restrict__ dinv, const _Float16* __restrict__ H,
    const float* __restrict__ bias, void* __restrict__ OUT, int n)
{
    constexpr int LPR = F / 8;     // lanes per row (16 or 8), 8 f16 per lane
    constexpr int GR  = 64 / LPR;  // rows per wave-load (4 or 8)
    int w = blockIdx.x * 4 + (threadIdx.x >> 6);
    if (w >= n) return;
    int lane = threadIdx.x & 63;
    int g = lane / LPR;
    int c = lane % LPR;            // uint4 slot within row
    float di = dinv[w];
    int s = rowptr[w], e = rowptr[w + 1];
    const uint4* Hp = reinterpret_cast<const uint4*>(H);

    float acc[8];
#pragma unroll
    for (int j = 0; j < 8; ++j) acc[j] = 0.f;
    uint4 hv = Hp[(size_t)w * LPR + c];                 // self row
    fma8(hv, (g == 0) ? di * di : 0.f, acc);

    for (int k = s; k < e; k += 2 * GR) {
        int k0 = k + g, k1 = k + GR + g;
        int kk0 = min(k0, e - 1), kk1 = min(k1, e - 1);
        int r0 = srows[kk0], r1 = srows[kk1];
        float w0 = (k0 < e) ? dinv[r0] * di : 0.f;
        float w1 = (k1 < e) ? dinv[r1] * di : 0.f;
        uint4 h0 = Hp[(size_t)r0 * LPR + c];
        uint4 h1 = Hp[(size_t)r1 * LPR + c];
        fma8(h0, w0, acc);
        fma8(h1, w1, acc);
    }

#pragma unroll
    for (int m = 32; m >= LPR; m >>= 1) {
#pragma unroll
        for (int j = 0; j < 8; ++j)
            acc[j] += __shfl_xor(acc[j], m, 64);
    }

    if (g == 0) {
        if constexpr (OUT_HALF) {
            union { uint4 u; __half2 h[4]; } P;
#pragma unroll
            for (int j = 0; j < 4; ++j)
                P.h[j] = __floats2half2_rn(acc[2 * j], acc[2 * j + 1]);
            reinterpret_cast<uint4*>(OUT)[(size_t)w * LPR + c] = P.u;
        } else {
            const float4* bp = reinterpret_cast<const float4*>(bias + c * 8);
            float4 b0 = bp[0], b1 = bp[1];
            float4 o0 = make_float4(acc[0] + b0.x, acc[1] + b0.y,
                                    acc[2] + b0.z, acc[3] + b0.w);
            float4 o1 = make_float4(acc[4] + b1.x, acc[5] + b1.y,
                                    acc[6] + b1.z, acc[7] + b1.w);
            float* op = (float*)OUT + (size_t)w * F + c * 8;
            *reinterpret_cast<float4*>(op)     = o0;
            *reinterpret_cast<float4*>(op + 4) = o1;
        }
    }
}

// ---------------- launch ----------------

extern "C" void kernel_launch(void* const* d_in, const int* in_sizes, int n_in,
                              void* d_out, int out_size, void* d_ws, size_t ws_size,
                              hipStream_t stream) {
    const float* x  = (const float*)d_in[0];
    const int*   ei = (const int*)  d_in[1];
    const float* W1 = (const float*)d_in[2];
    const float* b1 = (const float*)d_in[3];
    const float* W2 = (const float*)d_in[4];
    const float* b2 = (const float*)d_in[5];
    float* out = (float*)d_out;

    const int* row = ei;             // sources
    const int* col = ei + N_EDGES;   // targets

    // workspace layout
    char* ws = (char*)d_ws;
    int*   gcur   = (int*)ws;                                      // NBKT
    int*   rowptr = gcur + 512;                                    // N+1
    float* dinv   = (float*)(rowptr + ((N_NODES + 256) & ~255));   // N
    int*   srows  = (int*)(dinv + ((N_NODES + 255) & ~255));       // E
    _Float16* bufH   = (_Float16*)(srows + ((N_EDGES + 255) & ~255)); // N*128 f16
    _Float16* bufAgg = bufH + (size_t)N_NODES * 128;               // N*128 f16
    int*   pairs  = (int*)bufAgg;    // NBKT*CAP ints (7.2MB), dead before gather1

    // 1) zero bucket cursors; fused gemm1 + edge bucketing
    hipMemsetAsync(gcur, 0, NBKT * sizeof(int), stream);
    k_gemm1_bucket<<<G1_BLOCKS + NBLK_A, 256, 0, stream>>>(
        x, W1, bufH, row, col, gcur, pairs);

    // 2) CSR finalize: rowptr, dinv, srows
    k_fillB<<<NBKT, 256, 0, stream>>>(gcur, pairs, rowptr, dinv, srows);

    // 3) agg1 = gather(h1), f16 out
    k_gather_h<128, true><<<(N_NODES + 3) / 4, 256, 0, stream>>>(
        rowptr, srows, dinv, bufH, nullptr, bufAgg, N_NODES);

    // 4) h2 = relu(agg1+b1)@W2 (f16 out)
    k_gemm_mfma2<64><<<(N_NODES + 63) / 64, 256, 0, stream>>>(
        bufAgg, W2, b1, bufH, N_NODES);

    // 5) out = gather(h2) + b2 (fp32 out)
    k_gather_h<64, false><<<(N_NODES + 3) / 4, 256, 0, stream>>>(
        rowptr, srows, dinv, bufH, b2, out, N_NODES);
}